// Round 4
// baseline (981.980 us; speedup 1.0000x reference)
//
#include <hip/hip_runtime.h>
#include <hip/hip_bf16.h>

typedef unsigned short u16;
typedef unsigned char u8;
typedef __attribute__((ext_vector_type(8))) short bf16x8;
typedef __attribute__((ext_vector_type(4))) float f32x4;

#define MFMA16(a, b, c) __builtin_amdgcn_mfma_f32_16x16x32_bf16(a, b, c, 0, 0, 0)

static __device__ __forceinline__ u16 f2bf(float f) {
    __hip_bfloat16 h = __float2bfloat16(f);
    return *reinterpret_cast<u16*>(&h);
}
static __device__ __forceinline__ float bf2f(u16 h) {
    unsigned u = ((unsigned)h) << 16;
    return __uint_as_float(u);
}

// ---------------------------------------------------------------------------
// Kernel A: elementwise K fp32 -> bf16 into scratch (same [B,L,N,D] layout).
// ---------------------------------------------------------------------------
__global__ __launch_bounds__(256) void kconv_kernel(const float* __restrict__ kf,
                                                    u16* __restrict__ kb) {
    const size_t i = ((size_t)blockIdx.x * 256 + threadIdx.x) * 4;
    float4 f = *(const float4*)(kf + i);
    alignas(8) u16 w[4] = {f2bf(f.x), f2bf(f.y), f2bf(f.z), f2bf(f.w)};
    *(uint2*)(kb + i) = *(const uint2*)w;
}

// ---------------------------------------------------------------------------
// Kernel B: V fp32 [B,L,N,D] -> VT bf16 [B,N,D,L] (transpose + convert) so PV
// B-fragments are contiguous-in-j 16B loads.
// ---------------------------------------------------------------------------
__global__ __launch_bounds__(256) void vt_kernel(const float* __restrict__ v,
                                                 u16* __restrict__ vt) {
    __shared__ u16 T[64][72];
    const int t = threadIdx.x, bid = blockIdx.x;
    const int b = bid >> 9, n = bid & 15, j0 = ((bid >> 4) & 31) << 6;
    {
        const int jj = t >> 4, tt = t & 15;
#pragma unroll
        for (int rep = 0; rep < 4; rep++) {
            const int j = rep * 16 + jj;
            const float* src = v + (((size_t)((b * 2048 + j0 + j) * 16 + n)) << 6) + tt * 4;
            float4 f = *(const float4*)src;
            alignas(8) u16 w[4] = {f2bf(f.x), f2bf(f.y), f2bf(f.z), f2bf(f.w)};
            *(uint2*)&T[j][tt * 4] = *(const uint2*)w;
        }
    }
    __syncthreads();
    {
        const int d = t >> 2, jq = t & 3;
        alignas(16) u16 w[16];
#pragma unroll
        for (int e = 0; e < 16; e++) w[e] = T[jq * 16 + e][d];
        u16* dst = vt + (((size_t)((b * 16 + n) * 64 + d)) << 11) + j0 + jq * 16;
        *(uint4*)dst = *(const uint4*)&w[0];
        *(uint4*)(dst + 8) = *(const uint4*)&w[8];
    }
}

// ---------------------------------------------------------------------------
// Main fused attention kernel. fp32 outputs.
// Grid: 256 WGs. Block: 1024 threads = 16 waves = 16 heads.
// ---------------------------------------------------------------------------
__global__ __launch_bounds__(1024, 4) void attn_kernel(
    const float* __restrict__ qf, const u16* __restrict__ kb_g,
    const u16* __restrict__ vt, const void* __restrict__ mask,
    float* __restrict__ ctx, float* __restrict__ attn) {
    __shared__ u16 maskT[2048];        // bit i of maskT[j]: mask[b][i0+i][j]
    __shared__ u16 pbuf[16][16][40];   // [head][i][j-tile 32 + pad]

    const int tid = threadIdx.x;
    const int lane = tid & 63;
    const int wv = tid >> 6;  // head index
    const int g = lane >> 4, c = lane & 15;
    const int rbit = g * 4;

    const int bid = blockIdx.x;
    const int b = ((bid & 7) < 4) ? 0 : 1;             // XCDs 0-3: b=0, 4-7: b=1
    const int idx = ((bid >> 3) << 2) | (bid & 3);     // 0..127
    const int i0 = idx << 4;

    // --- probe mask dtype (wave-uniform) ---
    bool mask_is_u8;
    {
        unsigned acc = 0;
        const unsigned* mw = (const unsigned*)mask;
#pragma unroll
        for (int i = 0; i < 64; i++) acc |= mw[i];
        mask_is_u8 = (acc & 0xFFFFFF00u) != 0u;
    }

    // --- build mask bitmap (thread t covers j = 2t, 2t+1) ---
    {
        const size_t base = ((size_t)(b * 2048 + i0)) * 2048 + (size_t)tid * 2;
        unsigned m0 = 0, m1 = 0;
        if (mask_is_u8) {
            const u8* m8 = (const u8*)mask;
#pragma unroll
            for (int i = 0; i < 16; i++) {
                const u8* mp = m8 + base + (size_t)i * 2048;
                if (mp[0]) m0 |= (1u << i);
                if (mp[1]) m1 |= (1u << i);
            }
        } else {
            const int* m32 = (const int*)mask;
#pragma unroll
            for (int i = 0; i < 16; i++) {
                const int* mp = m32 + base + (size_t)i * 2048;
                if (mp[0]) m0 |= (1u << i);
                if (mp[1]) m1 |= (1u << i);
            }
        }
        *reinterpret_cast<unsigned*>(&maskT[tid * 2]) = m0 | (m1 << 16);
    }
    __syncthreads();

    // --- Q fragments (A-operand): lane holds Q[i0+c][d = g*8.. (+32)], fp32->bf16 ---
    bf16x8 aq0, aq1;
    {
        const float* qp = qf + (((size_t)(b * 2048 + i0 + c) * 16 + wv) << 6) + g * 8;
        float4 f0 = *(const float4*)qp;
        float4 f1 = *(const float4*)(qp + 4);
        float4 f2 = *(const float4*)(qp + 32);
        float4 f3 = *(const float4*)(qp + 36);
        alignas(16) u16 w0[8] = {f2bf(f0.x), f2bf(f0.y), f2bf(f0.z), f2bf(f0.w),
                                 f2bf(f1.x), f2bf(f1.y), f2bf(f1.z), f2bf(f1.w)};
        alignas(16) u16 w1[8] = {f2bf(f2.x), f2bf(f2.y), f2bf(f2.z), f2bf(f2.w),
                                 f2bf(f3.x), f2bf(f3.y), f2bf(f3.z), f2bf(f3.w)};
        aq0 = *(const bf16x8*)w0;
        aq1 = *(const bf16x8*)w1;
    }

    const u16* kb = kb_g + (((size_t)(b * 2048) * 16 + wv) << 6) + g * 8;
    const u16* vb = vt + (((size_t)(b * 16 + wv)) << 17);  // [b][n] plane, 64*2048

    // =================== Pass 1: row sums of exp ===================
    float l0 = 0.f, l1 = 0.f, l2 = 0.f, l3 = 0.f;
    for (int j0 = 0; j0 < 2048; j0 += 16) {
        const u16* kp = kb + (size_t)(j0 + c) * 1024;
        bf16x8 b0 = *(const bf16x8*)kp;
        bf16x8 b1 = *(const bf16x8*)(kp + 32);
        f32x4 s = {0.f, 0.f, 0.f, 0.f};
        s = MFMA16(aq0, b0, s);
        s = MFMA16(aq1, b1, s);
        const unsigned mt = maskT[j0 + c];
        l0 += __expf(((mt >> (rbit + 0)) & 1) ? -1e9f : s[0] * 0.125f);
        l1 += __expf(((mt >> (rbit + 1)) & 1) ? -1e9f : s[1] * 0.125f);
        l2 += __expf(((mt >> (rbit + 2)) & 1) ? -1e9f : s[2] * 0.125f);
        l3 += __expf(((mt >> (rbit + 3)) & 1) ? -1e9f : s[3] * 0.125f);
    }
#pragma unroll
    for (int off = 1; off <= 8; off <<= 1) {
        l0 += __shfl_xor(l0, off);
        l1 += __shfl_xor(l1, off);
        l2 += __shfl_xor(l2, off);
        l3 += __shfl_xor(l3, off);
    }
    const float n0i = (l0 != 0.f) ? 1.f / l0 : 0.f;
    const float n1i = (l1 != 0.f) ? 1.f / l1 : 0.f;
    const float n2i = (l2 != 0.f) ? 1.f / l2 : 0.f;
    const float n3i = (l3 != 0.f) ? 1.f / l3 : 0.f;

    // =================== Pass 2: write P, accumulate PV ===================
    f32x4 o0 = {0.f, 0.f, 0.f, 0.f}, o1 = o0, o2 = o0, o3 = o0;

    const int wo_i = tid >> 6;
    const int wo_c = tid & 63;
    const int wo_j = wo_c >> 1;
    const int wo_n = (wo_c & 1) << 3;
    float* attn_row = attn + (((size_t)(b * 2048 + i0 + wo_i)) << 15) + wo_n;

    for (int j0 = 0; j0 < 2048; j0 += 32) {
#pragma unroll
        for (int sub = 0; sub < 2; sub++) {
            const int jb = j0 + (sub << 4);
            const u16* kp = kb + (size_t)(jb + c) * 1024;
            bf16x8 b0 = *(const bf16x8*)kp;
            bf16x8 b1 = *(const bf16x8*)(kp + 32);
            f32x4 s = {0.f, 0.f, 0.f, 0.f};
            s = MFMA16(aq0, b0, s);
            s = MFMA16(aq1, b1, s);
            const unsigned mt = maskT[jb + c];
            const int jj = (sub << 4) + c;
            pbuf[wv][rbit + 0][jj] =
                f2bf(__expf(((mt >> (rbit + 0)) & 1) ? -1e9f : s[0] * 0.125f) * n0i);
            pbuf[wv][rbit + 1][jj] =
                f2bf(__expf(((mt >> (rbit + 1)) & 1) ? -1e9f : s[1] * 0.125f) * n1i);
            pbuf[wv][rbit + 2][jj] =
                f2bf(__expf(((mt >> (rbit + 2)) & 1) ? -1e9f : s[2] * 0.125f) * n2i);
            pbuf[wv][rbit + 3][jj] =
                f2bf(__expf(((mt >> (rbit + 3)) & 1) ? -1e9f : s[3] * 0.125f) * n3i);
        }
        __syncthreads();
        // PV: A = P (own head's pbuf, contiguous b128), B = VT (contiguous j)
        {
            const bf16x8 ap = *(const bf16x8*)&pbuf[wv][c][g * 8];
            const u16* vp = vb + (size_t)c * 2048 + j0 + g * 8;
            bf16x8 v0 = *(const bf16x8*)(vp);
            bf16x8 v1 = *(const bf16x8*)(vp + 16 * 2048);
            bf16x8 v2 = *(const bf16x8*)(vp + 32 * 2048);
            bf16x8 v3 = *(const bf16x8*)(vp + 48 * 2048);
            o0 = MFMA16(ap, v0, o0);
            o1 = MFMA16(ap, v1, o1);
            o2 = MFMA16(ap, v2, o2);
            o3 = MFMA16(ap, v3, o3);
        }
        // coalesced fp32 attention write: gather across heads, 32 B / thread
        {
            alignas(16) float w[8];
#pragma unroll
            for (int e = 0; e < 8; e++) w[e] = bf2f(pbuf[wo_n + e][wo_i][wo_j]);
            float* dst = attn_row + (size_t)(j0 + wo_j) * 16;
            *(float4*)dst = *(const float4*)&w[0];
            *(float4*)(dst + 4) = *(const float4*)&w[4];
        }
        __syncthreads();
    }

    // --- context epilogue (fp32): O[i = rbit+r][d = dt*16 + c] ---
#pragma unroll
    for (int r = 0; r < 4; r++) {
        float* cp = ctx + (((size_t)(b * 2048 + i0 + rbit + r) * 16 + wv) << 6) + c;
        cp[0]  = o0[r];
        cp[16] = o1[r];
        cp[32] = o2[r];
        cp[48] = o3[r];
    }
}

extern "C" void kernel_launch(void* const* d_in, const int* in_sizes, int n_in,
                              void* d_out, int out_size, void* d_ws, size_t ws_size,
                              hipStream_t stream) {
    const float* q   = (const float*)d_in[0];
    const float* k   = (const float*)d_in[1];
    const float* v   = (const float*)d_in[2];
    const void* mask = (const void*)d_in[3];

    float* ctx  = (float*)d_out;               // 2*2048*16*64    = 4,194,304 floats
    float* attn = (float*)d_out + 4194304;     // 2*2048*2048*16  = 134,217,728 floats

    u16* vt = (u16*)d_ws;                      // 8.39 MB bf16 VT [B,N,D,L]
    u16* kb = vt + 4194304;                    // 8.39 MB bf16 K  [B,L,N,D]

    kconv_kernel<<<4096, 256, 0, stream>>>(k, kb);
    vt_kernel<<<1024, 256, 0, stream>>>(v, vt);
    attn_kernel<<<256, 1024, 0, stream>>>(q, kb, vt, mask, ctx, attn);
}